// Round 8
// baseline (84.337 us; speedup 1.0000x reference)
//
#include <hip/hip_runtime.h>
#include <hip/hip_bf16.h>

#define TB 256

typedef __attribute__((ext_vector_type(8))) short short8;
typedef __attribute__((ext_vector_type(4))) unsigned int uint4v;
typedef __attribute__((ext_vector_type(4))) float f32x4;

// Problem constants: B=16, C=64, L=16384, HOP=256, KS=3, DIL=3, KL=64
// ws: ktf u32[16 b][96 chunk][64 f][128]  = 50,331,648 B   (chunk = (kk*4+jp)*4+hi)
//     wf  u32[6144]                        = 24,576 B
#define KTF_BYTES 50331648ull
#define WS_NEED   (KTF_BYTES + 24576ull)

static __device__ __forceinline__ float lrelu(float v){ return v > 0.f ? v : 0.2f*v; }

static __device__ __forceinline__ unsigned int pack2(float lo, float hi){
    __hip_bfloat162 h = __float22bfloat162_rn(float2{lo, hi});
    unsigned int r;
    __builtin_memcpy(&r, &h, 4);
    return r;
}

static __device__ __forceinline__ float bf2f(unsigned int u16v){
    return __uint_as_float(u16v << 16);
}

// sigmoid(a)*tanh(t) = (v-1) / ((1+u)(v+1)),  u=e^-a, v=e^{2t}
static __device__ __forceinline__ float glu_gate(float a, float t){
    t = fminf(fmaxf(t, -10.f), 10.f);
    float u = __expf(-a);
    float v = __expf(2.0f * t);
    float den = (1.0f + u) * (v + 1.0f);
    return (v - 1.0f) * __builtin_amdgcn_rcpf(den);
}

// ---------------------------------------------------------------------------
// A-frag pair: u32 = bf16{A[m][r], A[m][r+1]}, m = mt*16+lo, r = kk*32+hi*8+2jp
// ktf addr: ((b*96 + (kk*4+jp)*4 + hi)*64 + f)*128 + mt*16 + lo
//   -> transpose block (fixed kk,jp,hi) writes 512 B contiguous per f,
//      32 KB fully-sequential per block (DRAM-stream friendly)
// wf: idx = ((kk*4+jp)*4 + mt)*64 + ln   (mt 0..3)

__global__ __launch_bounds__(256, 4)
void ktf_transpose(const float* __restrict__ kern, unsigned int* __restrict__ ktf)
{
    __shared__ unsigned int tl32[128 * 65];            // [oc][f pad65], 33280 B
    const int tid = threadIdx.x;
    const int blk = blockIdx.x;                        // 1536 = b*96 + ci2*3 + k
    const int k   = blk % 3;
    const int ci2 = (blk / 3) % 32;
    const int b   = blk / 96;
    const int kk  = k*2 + (ci2 >> 4);
    const int hi  = (ci2 >> 2) & 3;
    const int jp  = ci2 & 3;

    const float* src0 = kern + (size_t)b*1572864 + (size_t)ci2*49152 + k*64;
    #pragma unroll
    for (int it = 0; it < 8; ++it) {
        int p = tid + it*TB;                           // 2048 = 128 oc * 16 fq
        int oc = p >> 4, fq = p & 15;
        const float* s = src0 + oc*192 + fq*4;
        float4 v0 = *(const float4*)(s);               // ci even
        float4 v1 = *(const float4*)(s + 24576);       // ci odd
        unsigned int* d = tl32 + oc*65 + fq*4;
        d[0] = pack2(v0.x, v1.x);
        d[1] = pack2(v0.y, v1.y);
        d[2] = pack2(v0.z, v1.z);
        d[3] = pack2(v0.w, v1.w);
    }
    __syncthreads();

    const int l = tid & 63, wv = tid >> 6;
    const int c = (kk*4 + jp)*4 + hi;
    unsigned int* dst = ktf + (size_t)(b*96 + c)*8192 + 2*l;
    const int f0 = wv*16;
    #pragma unroll
    for (int fi = 0; fi < 16; ++fi) {
        int f = f0 + fi;
        uint2 v;
        v.x = tl32[(2*l    )*65 + f];
        v.y = tl32[(2*l + 1)*65 + f];
        *(uint2*)(dst + f*128) = v;                    // 512 B contiguous per wave-instr
    }
}

// conv_w[co][ci][k] -> wf
__global__ __launch_bounds__(256, 4)
void wf_prep(const float* __restrict__ conv_w, unsigned int* __restrict__ wf)
{
    int u = blockIdx.x*TB + threadIdx.x;               // 6144
    int ln = u & 63, mt = (u >> 6) & 3, jp = (u >> 8) & 3, kk = u >> 10;
    int lo = ln & 15, hi = ln >> 4;
    int m  = mt*16 + lo;
    int k  = kk >> 1, ci = (kk & 1)*32 + hi*8 + jp*2;
    float a0 = conv_w[m*192 + ci*3 + k];
    float a1 = conv_w[m*192 + (ci + 1)*3 + k];
    wf[u] = pack2(a0, a1);
}

// ---------------------------------------------------------------------------
// LDS: xt[288][64ci] bf16 swizzled @0 (36864B)   [lrelu'd x; also resid source]
//      ht[272][64]  bf16 swizzled @36864 (34816B)
//      bias_lds[128] f32 @71680
#define LDS_BYTES (36864 + 34816 + 512)

__global__ __launch_bounds__(512, 4)
void fused_kernel(const float* __restrict__ x,
                  const float* __restrict__ bias,
                  const float* __restrict__ conv_b,
                  const unsigned int* __restrict__ ktf,
                  const unsigned int* __restrict__ wf,
                  float* __restrict__ out)
{
    __shared__ char lds[LDS_BYTES];
    float* bias_lds = (float*)(lds + 71680);

    const int tid = threadIdx.x;
    const int blk = blockIdx.x;                        // 1024 = b*64 + f
    const int b = blk >> 6, f = blk & 63;
    const int t0 = f << 8;
    const int ln = tid & 63, wv = tid >> 6;            // 8 waves
    const int lo = ln & 15, hi = ln >> 4;
    const int mt = wv & 3, nth = wv >> 2;

    // ---- A1: issue x-tile loads FIRST (oldest in vmcnt order) ----
    const int g = wv;
    const float* xb = x + ((size_t)b*64 + g*8) * 16384;
    float2 xv[24];
    {
        const bool interior = (f > 0) & (f < 63);
        if (interior) {
            #pragma unroll
            for (int it = 0; it < 3; ++it) {
                if (it < 2 || ln < 16) {
                    int t = t0 - 12 + 2*ln + it*128;
                    #pragma unroll
                    for (int j = 0; j < 8; ++j)
                        xv[it*8 + j] = *(const float2*)(xb + j*16384 + t);
                }
            }
        } else {
            #pragma unroll
            for (int it = 0; it < 3; ++it) {
                if (it < 2 || ln < 16) {
                    int t = t0 - 12 + 2*ln + it*128;
                    #pragma unroll
                    for (int j = 0; j < 8; ++j) {
                        float a = ((unsigned)t       < 16384u) ? xb[j*16384 + t    ] : 0.f;
                        float c = ((unsigned)(t + 1) < 16384u) ? xb[j*16384 + t + 1] : 0.f;
                        xv[it*8 + j] = make_float2(a, c);
                    }
                }
            }
        }
        if (tid < 128) bias_lds[tid] = bias[(size_t)b*8192 + tid*64 + f];
    }
    __builtin_amdgcn_sched_barrier(0);

    // ---- A2: issue aw loads (needed in B) ----
    uint4v aw[6];
    #pragma unroll
    for (int kk = 0; kk < 6; ++kk) {
        int w0 = kk*1024 + mt*64 + ln;                 // jp stride 256
        aw[kk].x = wf[w0      ]; aw[kk].y = wf[w0 + 256];
        aw[kk].z = wf[w0 + 512]; aw[kk].w = wf[w0 + 768];
    }
    __builtin_amdgcn_sched_barrier(0);

    // ---- A3: convert x -> xt (lrelu, bf16, swizzled); frees xv regs ----
    #pragma unroll
    for (int it = 0; it < 3; ++it) {
        if (it < 2 || ln < 16) {
            int p0 = 2*ln + it*128;
            unsigned int w0[4], w1[4];
            #pragma unroll
            for (int jq = 0; jq < 4; ++jq) {
                float2 e0 = xv[it*8 + 2*jq], e1 = xv[it*8 + 2*jq + 1];
                w0[jq] = pack2(lrelu(e0.x), lrelu(e1.x));
                w1[jq] = pack2(lrelu(e0.y), lrelu(e1.y));
            }
            int a0 = ( p0     *128 + g*16) ^ (( p0      & 7) << 4);
            int a1 = ((p0 + 1)*128 + g*16) ^ (((p0 + 1) & 7) << 4);
            *(uint4*)(lds + a0) = make_uint4(w0[0], w0[1], w0[2], w0[3]);
            *(uint4*)(lds + a1) = make_uint4(w1[0], w1[1], w1[2], w1[3]);
        }
    }
    __builtin_amdgcn_sched_barrier(0);

    // ---- A4: issue am loads (needed in C; latency hides under B) ----
    // addr = b*786432 + ((kk*4+jp)*4+hi)*8192 + f*128 + mt*16 + lo
    uint4v am0[6], am1[6];
    {
        const unsigned int* kp = ktf + (size_t)b*786432 + f*128 + hi*8192 + mt*16 + lo;
        #pragma unroll
        for (int kk = 0; kk < 6; ++kk) {
            int o = kk*131072;                         // jp stride 32768
            am0[kk].x = kp[o         ]; am0[kk].y = kp[o +  32768];
            am0[kk].z = kp[o +  65536]; am0[kk].w = kp[o +  98304];
            am1[kk].x = kp[o +     64]; am1[kk].y = kp[o +  32832];
            am1[kk].z = kp[o +  65600]; am1[kk].w = kp[o +  98368];
        }
    }
    __syncthreads();

    // ---- Phase B: dilated conv via MFMA; wave (mt, nth); writes ht ----
    {
        float4 cb4 = *(const float4*)(conv_b + mt*16 + hi*4);
        const int n0  = nth ? 9 : 0;
        const int cnt = nth ? 8 : 9;                   // nt 0..8 | 9..16
        int bqa[6];
        #pragma unroll
        for (int kk = 0; kk < 6; ++kk) {
            int row = n0*16 + lo + 3*(kk >> 1) + 1;    // row&7 invariant across nt
            int cib = (kk & 1)*32 + hi*8;
            bqa[kk] = (row*128 + cib*2) ^ ((row & 7) << 4);
        }
        int hta  = 36864 + (((n0*16 + lo)*128 + (mt*16 + hi*4)*2) ^ ((lo & 7) << 4));
        int pos  = t0 + n0*16 + lo - 8;
        #pragma unroll 1
        for (int i = 0; i < cnt; ++i) {
            short8 bq[6];
            #pragma unroll
            for (int kk = 0; kk < 6; ++kk)
                bq[kk] = *(const short8*)(lds + bqa[kk]);
            f32x4 acc = {0.f, 0.f, 0.f, 0.f};
            __builtin_amdgcn_s_setprio(1);
            #pragma unroll
            for (int kk = 0; kk < 6; ++kk)
                acc = __builtin_amdgcn_mfma_f32_16x16x32_bf16(
                        __builtin_bit_cast(short8, aw[kk]), bq[kk], acc, 0, 0, 0);
            __builtin_amdgcn_s_setprio(0);

            bool valid = (unsigned)pos < 16384u;
            unsigned int h01 = valid ? pack2(lrelu(acc[0] + cb4.x), lrelu(acc[1] + cb4.y)) : 0u;
            unsigned int h23 = valid ? pack2(lrelu(acc[2] + cb4.z), lrelu(acc[3] + cb4.w)) : 0u;
            unsigned int* d = (unsigned int*)(lds + hta);
            d[0] = h01; d[1] = h23;

            #pragma unroll
            for (int kk = 0; kk < 6; ++kk) bqa[kk] += 2048;
            hta += 2048; pos += 16;
        }
    }
    __syncthreads();

    // ---- Phase C: LVC via MFMA; wave (mt,nth) owns oc-tiles {mt, mt+4} ----
    {
        float ba[4], bb[4];
        size_t rowbase[4];
        #pragma unroll
        for (int r = 0; r < 4; ++r) {
            int c = mt*16 + hi*4 + r;
            ba[r] = bias_lds[c];
            bb[r] = bias_lds[c + 64];
            rowbase[r] = (size_t)(b*64 + c)*16384 + t0 + nth*128 + lo;
        }
        int bqa[6];
        #pragma unroll
        for (int kk = 0; kk < 6; ++kk) {
            int row = nth*128 + lo + (kk >> 1) + 7;    // row&7 invariant across i
            int cib = (kk & 1)*32 + hi*8;
            bqa[kk] = 36864 + ((row*128 + cib*2) ^ ((row & 7) << 4));
        }
        int prow = nth*128 + lo + 12;
        int ra   = (prow*128 + (mt*16 + hi*4)*2) ^ ((prow & 7) << 4);

        #pragma unroll 1
        for (int i = 0; i < 8; ++i) {
            short8 bq[6];
            #pragma unroll
            for (int kk = 0; kk < 6; ++kk)
                bq[kk] = *(const short8*)(lds + bqa[kk]);
            // residual from live xt tile (lrelu is invertible)
            uint2 rv = *(const uint2*)(lds + ra);

            f32x4 a0 = {0.f,0.f,0.f,0.f}, a1 = {0.f,0.f,0.f,0.f};
            __builtin_amdgcn_s_setprio(1);
            #pragma unroll
            for (int kk = 0; kk < 6; ++kk) {
                a0 = __builtin_amdgcn_mfma_f32_16x16x32_bf16(
                        __builtin_bit_cast(short8, am0[kk]), bq[kk], a0, 0, 0, 0);
                a1 = __builtin_amdgcn_mfma_f32_16x16x32_bf16(
                        __builtin_bit_cast(short8, am1[kk]), bq[kk], a1, 0, 0, 0);
            }
            __builtin_amdgcn_s_setprio(0);

            #pragma unroll
            for (int r = 0; r < 4; ++r) {
                unsigned int u = (r < 2 ? rv.x : rv.y) >> ((r & 1) * 16);
                float hv = bf2f(u & 0xFFFFu);
                float xr = hv > 0.f ? hv : 5.0f * hv;  // inverse lrelu
                float gg = glu_gate(a0[r] + ba[r], a1[r] + bb[r]);
                out[rowbase[r] + (size_t)i*16] = xr + gg;
            }
            #pragma unroll
            for (int kk = 0; kk < 6; ++kk) bqa[kk] += 2048;
            ra += 2048;
        }
    }
}

extern "C" void kernel_launch(void* const* d_in, const int* in_sizes, int n_in,
                              void* d_out, int out_size, void* d_ws, size_t ws_size,
                              hipStream_t stream)
{
    const float* x      = (const float*)d_in[0];
    const float* kern   = (const float*)d_in[1];
    const float* bias   = (const float*)d_in[2];
    const float* conv_b = (const float*)d_in[4];
    float* out = (float*)d_out;

    if (ws_size < WS_NEED) return;   // harness provides >=100MB (verified R0)

    unsigned int* ktf = (unsigned int*)d_ws;
    unsigned int* wf  = (unsigned int*)((char*)d_ws + KTF_BYTES);

    wf_prep      <<<dim3(24),   dim3(TB), 0, stream>>>((const float*)d_in[3], wf);
    ktf_transpose<<<dim3(1536), dim3(TB), 0, stream>>>(kern, ktf);
    fused_kernel <<<dim3(1024), dim3(512), 0, stream>>>(x, bias, conv_b, ktf, wf, out);
    (void)in_sizes; (void)n_in; (void)out_size;
}